// Round 5
// baseline (245.655 us; speedup 1.0000x reference)
//
#include <hip/hip_runtime.h>
#include <hip/hip_bf16.h>

#define N_NODES 50000
#define N_EDGES 600000
#define N_GRAPHS 1000
#define IN_DIM 100
#define HID 128
#define OUT_DIM 128
#define KP 128   // padded K for transposed weight planes

typedef __attribute__((ext_vector_type(8))) short bf16x8;
typedef __attribute__((ext_vector_type(4))) float f32x4;

__device__ inline unsigned short f2bf(float f) {
    __hip_bfloat16 b = __float2bfloat16(f);
    return *reinterpret_cast<unsigned short*>(&b);
}
__device__ inline float bf2f(unsigned short u) { return __uint_as_float(((unsigned int)u) << 16); }
__device__ inline float bflo(unsigned int u) { return __uint_as_float(u << 16); }
__device__ inline float bfhi(unsigned int u) { return __uint_as_float(u & 0xffff0000u); }

// ---------------- degree (int) ----------------
__global__ __launch_bounds__(256) void deg_count(const int* __restrict__ dst, int* __restrict__ deg) {
    int e = blockIdx.x * 256 + threadIdx.x;
    if (e < N_EDGES) atomicAdd(&deg[dst[e]], 1);
}

// ---------------- range allocator + dinv ----------------
__global__ __launch_bounds__(256) void alloc_off(const int* __restrict__ deg,
                                                 int* __restrict__ off,
                                                 int* __restrict__ total,
                                                 float* __restrict__ dinv) {
    int i = blockIdx.x * 256 + threadIdx.x;
    int v = (i < N_NODES) ? deg[i] : 0;
    int lane = threadIdx.x & 63;
    int wid  = threadIdx.x >> 6;
    int x = v;
#pragma unroll
    for (int d = 1; d < 64; d <<= 1) {
        int y = __shfl_up(x, d, 64);
        if (lane >= d) x += y;
    }
    __shared__ int wsum[4];
    __shared__ int wbase[4];
    if (lane == 63) wsum[wid] = x;
    __syncthreads();
    if (threadIdx.x == 0) {
        int s0 = wsum[0], s1 = wsum[1], s2 = wsum[2], s3 = wsum[3];
        int base = atomicAdd(total, s0 + s1 + s2 + s3);
        wbase[0] = base;
        wbase[1] = base + s0;
        wbase[2] = base + s0 + s1;
        wbase[3] = base + s0 + s1 + s2;
    }
    __syncthreads();
    if (i < N_NODES) {
        off[i] = wbase[wid] + x - v;
        dinv[i] = rsqrtf((float)v + 1.0f);
    }
}

// ---------------- fill CSR: csr_src grouped by dst ----------------
__global__ __launch_bounds__(256) void fill_csr(
    const int* __restrict__ src, const int* __restrict__ dst,
    const int* __restrict__ off, int* __restrict__ cursor, int* __restrict__ csr_src)
{
    int e = blockIdx.x * 256 + threadIdx.x;
    if (e >= N_EDGES) return;
    int d = dst[e];
    int pos = off[d] + atomicAdd(&cursor[d], 1);
    csr_src[pos] = src[e];
}

// ---------------- graph segment boundaries from sorted batch ----------------
__global__ __launch_bounds__(256) void graph_bounds(const int* __restrict__ batch, int* __restrict__ starts) {
    int i = blockIdx.x * 256 + threadIdx.x;
    if (i >= N_NODES) return;
    int b = batch[i];
    if (i == 0) {
        for (int g = 0; g <= b; ++g) starts[g] = 0;
    } else {
        int pb = batch[i - 1];
        for (int g = pb + 1; g <= b; ++g) starts[g] = i;
    }
    if (i == N_NODES - 1) {
        for (int g = b + 1; g <= N_GRAPHS; ++g) starts[g] = N_NODES;
    }
}

// ---------------- weight split+transpose: W[K][128] f32 -> Wt_hi/Wt_lo[n][KP] bf16 ----
__global__ __launch_bounds__(256) void conv_w(const float* __restrict__ W, int K,
                                              unsigned short* __restrict__ WtH,
                                              unsigned short* __restrict__ WtL) {
    int idx = blockIdx.x * 256 + threadIdx.x;   // over 128*KP
    if (idx >= 128 * KP) return;
    int n = idx >> 7;          // KP==128
    int k = idx & (KP - 1);
    float v = (k < K) ? W[(size_t)k * 128 + n] : 0.0f;
    unsigned short hi = f2bf(v);
    float fhi = bf2f(hi);
    unsigned short lo = f2bf(v - fhi);
    WtH[idx] = hi;
    WtL[idx] = lo;
}

// ---------------- MFMA GEMM: hb = bf16( (A@W) * dinv[row] ), split-bf16 3-term ----
__global__ __launch_bounds__(256) void gemm_mfma(
    const float* __restrict__ A, int K, int M,
    const unsigned short* __restrict__ WtH, const unsigned short* __restrict__ WtL,
    const float* __restrict__ dinv, unsigned int* __restrict__ hb)
{
    const int wid  = threadIdx.x >> 6;
    const int lane = threadIdx.x & 63;
    const int row_in = lane & 15;     // A row within 16 / B col within 16
    const int kgrp   = lane >> 4;     // 0..3 (8 k's each)
    const int m = blockIdx.x * 64 + wid * 16 + row_in;

    f32x4 acc[8];
#pragma unroll
    for (int nb = 0; nb < 8; nb++) acc[nb] = (f32x4){0.f, 0.f, 0.f, 0.f};

    for (int k0 = 0; k0 < K; k0 += 32) {
        int kb = k0 + kgrp * 8;
        float av[8];
#pragma unroll
        for (int i = 0; i < 8; i++) av[i] = 0.f;
        if (m < M) {
            if (kb + 8 <= K) {
                const float4* p = reinterpret_cast<const float4*>(A + (size_t)m * K + kb);
                float4 x0 = p[0], x1 = p[1];
                av[0] = x0.x; av[1] = x0.y; av[2] = x0.z; av[3] = x0.w;
                av[4] = x1.x; av[5] = x1.y; av[6] = x1.z; av[7] = x1.w;
            } else {
#pragma unroll
                for (int i = 0; i < 8; i++)
                    if (kb + i < K) av[i] = A[(size_t)m * K + kb + i];
            }
        }
        union { unsigned short u[8]; bf16x8 v; } ah, al;
#pragma unroll
        for (int i = 0; i < 8; i++) {
            unsigned short h = f2bf(av[i]);
            ah.u[i] = h;
            al.u[i] = f2bf(av[i] - bf2f(h));
        }
#pragma unroll
        for (int nb = 0; nb < 8; nb++) {
            const size_t wo = (size_t)(nb * 16 + row_in) * KP + kb;
            union { const unsigned short* p; const bf16x8* v; } bh, bl;
            bh.p = WtH + wo;
            bl.p = WtL + wo;
            acc[nb] = __builtin_amdgcn_mfma_f32_16x16x32_bf16(ah.v, *bh.v, acc[nb], 0, 0, 0);
            acc[nb] = __builtin_amdgcn_mfma_f32_16x16x32_bf16(ah.v, *bl.v, acc[nb], 0, 0, 0);
            acc[nb] = __builtin_amdgcn_mfma_f32_16x16x32_bf16(al.v, *bh.v, acc[nb], 0, 0, 0);
        }
    }

    // epilogue: C/D layout col=lane&15, row=(lane>>4)*4+r  -> LDS -> packed bf16 store
    __shared__ float C[64][132];
#pragma unroll
    for (int nb = 0; nb < 8; nb++)
#pragma unroll
        for (int r = 0; r < 4; r++)
            C[wid * 16 + kgrp * 4 + r][nb * 16 + row_in] = acc[nb][r];
    __syncthreads();

    int row = threadIdx.x >> 2;
    int c0  = (threadIdx.x & 3) * 32;
    int gm  = blockIdx.x * 64 + row;
    if (gm < M) {
        float dv = dinv[gm];
        unsigned int* orow = hb + (size_t)gm * 64 + (c0 >> 1);
#pragma unroll
        for (int q = 0; q < 4; q++) {
            float4 v0 = *reinterpret_cast<float4*>(&C[row][c0 + q * 8]);
            float4 v1 = *reinterpret_cast<float4*>(&C[row][c0 + q * 8 + 4]);
            uint4 pk;
            pk.x = (unsigned int)f2bf(v0.x * dv) | ((unsigned int)f2bf(v0.y * dv) << 16);
            pk.y = (unsigned int)f2bf(v0.z * dv) | ((unsigned int)f2bf(v0.w * dv) << 16);
            pk.z = (unsigned int)f2bf(v1.x * dv) | ((unsigned int)f2bf(v1.y * dv) << 16);
            pk.w = (unsigned int)f2bf(v1.z * dv) | ((unsigned int)f2bf(v1.w * dv) << 16);
            *reinterpret_cast<uint4*>(orow + q * 4) = pk;
        }
    }
}

// ---- gather: out[d] = relu( dd * (sum_{e:dst=d} h'[src] + h'[d]) + b ), h' in bf16 ----
__global__ __launch_bounds__(256) void gather_agg(
    const uint2* __restrict__ hp, const float* __restrict__ dinv,
    const int* __restrict__ off, const int* __restrict__ deg,
    const int* __restrict__ csr_src,
    const float* __restrict__ bias, float* __restrict__ out)
{
    int gid = blockIdx.x * 256 + threadIdx.x;
    int node = gid >> 5;
    if (node >= N_NODES) return;
    int lane = gid & 31;

    int beg = off[node];
    int end = beg + deg[node];
    float dd = dinv[node];

    uint2 self = hp[(size_t)node * 32 + lane];
    float4 a0 = make_float4(bflo(self.x), bfhi(self.x), bflo(self.y), bfhi(self.y));
    float4 a1 = make_float4(0.f, 0.f, 0.f, 0.f);
    float4 a2 = make_float4(0.f, 0.f, 0.f, 0.f);
    float4 a3 = make_float4(0.f, 0.f, 0.f, 0.f);

    int j = beg;
    for (; j + 3 < end; j += 4) {
        int s0 = csr_src[j + 0];
        int s1 = csr_src[j + 1];
        int s2 = csr_src[j + 2];
        int s3 = csr_src[j + 3];
        uint2 v0 = hp[(size_t)s0 * 32 + lane];
        uint2 v1 = hp[(size_t)s1 * 32 + lane];
        uint2 v2 = hp[(size_t)s2 * 32 + lane];
        uint2 v3 = hp[(size_t)s3 * 32 + lane];
        a0.x += bflo(v0.x); a0.y += bfhi(v0.x); a0.z += bflo(v0.y); a0.w += bfhi(v0.y);
        a1.x += bflo(v1.x); a1.y += bfhi(v1.x); a1.z += bflo(v1.y); a1.w += bfhi(v1.y);
        a2.x += bflo(v2.x); a2.y += bfhi(v2.x); a2.z += bflo(v2.y); a2.w += bfhi(v2.y);
        a3.x += bflo(v3.x); a3.y += bfhi(v3.x); a3.z += bflo(v3.y); a3.w += bfhi(v3.y);
    }
    for (; j < end; ++j) {
        int s = csr_src[j];
        uint2 v = hp[(size_t)s * 32 + lane];
        a0.x += bflo(v.x); a0.y += bfhi(v.x); a0.z += bflo(v.y); a0.w += bfhi(v.y);
    }
    a0.x += a1.x + a2.x + a3.x;
    a0.y += a1.y + a2.y + a3.y;
    a0.z += a1.z + a2.z + a3.z;
    a0.w += a1.w + a2.w + a3.w;

    float4 bb = *reinterpret_cast<const float4*>(bias + lane * 4);
    float4 o = make_float4(fmaxf(a0.x * dd + bb.x, 0.f),
                           fmaxf(a0.y * dd + bb.y, 0.f),
                           fmaxf(a0.z * dd + bb.z, 0.f),
                           fmaxf(a0.w * dd + bb.w, 0.f));
    *reinterpret_cast<float4*>(out + (size_t)node * HID + lane * 4) = o;
}

// ---------------- fused mean-pool + head ----------------
__global__ __launch_bounds__(128) void pool_head(
    const float* __restrict__ xbuf, const int* __restrict__ starts,
    const float* __restrict__ Wp, const float* __restrict__ bp,
    float* __restrict__ out)
{
    __shared__ float p[128];
    int g = blockIdx.x;
    int t = threadIdx.x;
    int s0 = starts[g], s1 = starts[g + 1];
    float acc = 0.f;
    for (int n = s0; n < s1; ++n) acc += xbuf[(size_t)n * HID + t];
    float cntf = (float)(s1 - s0);
    p[t] = acc / fmaxf(cntf, 1.0f);
    __syncthreads();
    float o = bp[t];
#pragma unroll 8
    for (int k = 0; k < HID; k++) o += p[k] * Wp[(size_t)k * OUT_DIM + t];
    out[(size_t)g * OUT_DIM + t] = o;
}

extern "C" void kernel_launch(void* const* d_in, const int* in_sizes, int n_in,
                              void* d_out, int out_size, void* d_ws, size_t ws_size,
                              hipStream_t stream) {
    const float* x   = (const float*)d_in[0];
    const int*   ei  = (const int*)d_in[1];
    const int*   src = ei;
    const int*   dst = ei + N_EDGES;
    const int*   batch = (const int*)d_in[2];
    const float* W1 = (const float*)d_in[3];
    const float* b1 = (const float*)d_in[4];
    const float* W2 = (const float*)d_in[5];
    const float* b2 = (const float*)d_in[6];
    const float* Wp = (const float*)d_in[7];
    const float* bp = (const float*)d_in[8];
    float* out = (float*)d_out;

    // ---- workspace layout (4-byte units) ----
    float* ws     = (float*)d_ws;
    float* dinv   = ws;                          // 50,048
    int*   deg    = (int*)(ws + 50048);          // 50,048
    int*   total  = deg + 50048;                 // 32 (1 used)
    int*   off    = total + 32;                  // 50,056
    int*   csr_src= off + 50056;                 // 600,000
    int*   starts = csr_src + 600000;            // 1,024 (1001 used)
    unsigned short* wt1h = (unsigned short*)(starts + 1024);   // 16,384 u16
    unsigned short* wt1l = wt1h + 128 * KP;
    unsigned short* wt2h = wt1l + 128 * KP;
    unsigned short* wt2l = wt2h + 128 * KP;
    unsigned int* hb = (unsigned int*)(wt2l + 128 * KP);       // 3,200,000 u32
    float* xbuf   = (float*)(hb + 3200000);      // 6,400,000 f
    // alias: cursor lives in xbuf until gather1 writes xbuf
    int*   cursor = (int*)xbuf;

    // ---- CSR build ----
    hipMemsetAsync(deg, 0, (50048 + 32) * sizeof(int), stream);   // deg + total
    deg_count<<<(N_EDGES + 255) / 256, 256, 0, stream>>>(dst, deg);
    alloc_off<<<(N_NODES + 255) / 256, 256, 0, stream>>>(deg, off, total, dinv);
    hipMemsetAsync(cursor, 0, N_NODES * sizeof(int), stream);
    fill_csr<<<(N_EDGES + 255) / 256, 256, 0, stream>>>(src, dst, off, cursor, csr_src);
    graph_bounds<<<(N_NODES + 255) / 256, 256, 0, stream>>>(batch, starts);

    // ---- weight prep ----
    conv_w<<<(128 * KP + 255) / 256, 256, 0, stream>>>(W1, IN_DIM, wt1h, wt1l);
    conv_w<<<(128 * KP + 255) / 256, 256, 0, stream>>>(W2, HID, wt2h, wt2l);

    const int gemm_blocks = (N_NODES + 63) / 64;
    const int gather_blocks = (N_NODES * 32 + 255) / 256;

    // ---- layer 1 ----
    gemm_mfma<<<gemm_blocks, 256, 0, stream>>>(x, IN_DIM, N_NODES, wt1h, wt1l, dinv, hb);
    gather_agg<<<gather_blocks, 256, 0, stream>>>((const uint2*)hb, dinv, off, deg, csr_src, b1, xbuf);

    // ---- layer 2 ----
    gemm_mfma<<<gemm_blocks, 256, 0, stream>>>(xbuf, HID, N_NODES, wt2h, wt2l, dinv, hb);
    gather_agg<<<gather_blocks, 256, 0, stream>>>((const uint2*)hb, dinv, off, deg, csr_src, b2, xbuf);

    // ---- pool + head ----
    pool_head<<<N_GRAPHS, 128, 0, stream>>>(xbuf, starts, Wp, bp, out);
}

// Round 6
// 234.491 us; speedup vs baseline: 1.0476x; 1.0476x over previous
//
#include <hip/hip_runtime.h>
#include <hip/hip_bf16.h>

#define N_NODES 50000
#define N_EDGES 600000
#define N_GRAPHS 1000
#define IN_DIM 100
#define HID 128
#define OUT_DIM 128
#define KP 128   // padded K for transposed weight planes

typedef __attribute__((ext_vector_type(8))) short bf16x8;
typedef __attribute__((ext_vector_type(4))) float f32x4;

__device__ inline unsigned short f2bf(float f) {
    __hip_bfloat16 b = __float2bfloat16(f);
    return *reinterpret_cast<unsigned short*>(&b);
}
__device__ inline float bf2f(unsigned short u) { return __uint_as_float(((unsigned int)u) << 16); }
__device__ inline float bflo(unsigned int u) { return __uint_as_float(u << 16); }
__device__ inline float bfhi(unsigned int u) { return __uint_as_float(u & 0xffff0000u); }

// ---------------- zero deg+total (replaces 40us hipMemsetAsync) ----------------
__global__ __launch_bounds__(256) void zero_meta(int* __restrict__ deg_total) {
    int i = blockIdx.x * 256 + threadIdx.x;      // over (50048+32)/4 int4
    int4* p = reinterpret_cast<int4*>(deg_total);
    if (i < (50048 + 32) / 4) p[i] = make_int4(0, 0, 0, 0);
}

// ---------------- degree (int) ----------------
__global__ __launch_bounds__(256) void deg_count(const int* __restrict__ dst, int* __restrict__ deg) {
    int e = blockIdx.x * 256 + threadIdx.x;
    if (e < N_EDGES) atomicAdd(&deg[dst[e]], 1);
}

// ---------------- range allocator + dinv + cursor zero ----------------
__global__ __launch_bounds__(256) void alloc_off(const int* __restrict__ deg,
                                                 int* __restrict__ off,
                                                 int* __restrict__ total,
                                                 float* __restrict__ dinv,
                                                 int* __restrict__ cursor) {
    int i = blockIdx.x * 256 + threadIdx.x;
    int v = (i < N_NODES) ? deg[i] : 0;
    int lane = threadIdx.x & 63;
    int wid  = threadIdx.x >> 6;
    int x = v;
#pragma unroll
    for (int d = 1; d < 64; d <<= 1) {
        int y = __shfl_up(x, d, 64);
        if (lane >= d) x += y;
    }
    __shared__ int wsum[4];
    __shared__ int wbase[4];
    if (lane == 63) wsum[wid] = x;
    __syncthreads();
    if (threadIdx.x == 0) {
        int s0 = wsum[0], s1 = wsum[1], s2 = wsum[2], s3 = wsum[3];
        int base = atomicAdd(total, s0 + s1 + s2 + s3);
        wbase[0] = base;
        wbase[1] = base + s0;
        wbase[2] = base + s0 + s1;
        wbase[3] = base + s0 + s1 + s2;
    }
    __syncthreads();
    if (i < N_NODES) {
        off[i] = wbase[wid] + x - v;
        dinv[i] = rsqrtf((float)v + 1.0f);
        cursor[i] = 0;
    }
}

// ---------------- fill CSR: csr_src grouped by dst ----------------
__global__ __launch_bounds__(256) void fill_csr(
    const int* __restrict__ src, const int* __restrict__ dst,
    const int* __restrict__ off, int* __restrict__ cursor, int* __restrict__ csr_src)
{
    int e = blockIdx.x * 256 + threadIdx.x;
    if (e >= N_EDGES) return;
    int d = dst[e];
    int pos = off[d] + atomicAdd(&cursor[d], 1);
    csr_src[pos] = src[e];
}

// ---------------- graph segment boundaries from sorted batch ----------------
__global__ __launch_bounds__(256) void graph_bounds(const int* __restrict__ batch, int* __restrict__ starts) {
    int i = blockIdx.x * 256 + threadIdx.x;
    if (i >= N_NODES) return;
    int b = batch[i];
    if (i == 0) {
        for (int g = 0; g <= b; ++g) starts[g] = 0;
    } else {
        int pb = batch[i - 1];
        for (int g = pb + 1; g <= b; ++g) starts[g] = i;
    }
    if (i == N_NODES - 1) {
        for (int g = b + 1; g <= N_GRAPHS; ++g) starts[g] = N_NODES;
    }
}

// ------- weight split+transpose, both layers in one launch -------
__global__ __launch_bounds__(256) void conv_w2(const float* __restrict__ W1, int K1,
                                               const float* __restrict__ W2, int K2,
                                               unsigned short* __restrict__ WtH1,
                                               unsigned short* __restrict__ WtL1,
                                               unsigned short* __restrict__ WtH2,
                                               unsigned short* __restrict__ WtL2) {
    int idx = blockIdx.x * 256 + threadIdx.x;   // over 2*128*KP
    if (idx >= 2 * 128 * KP) return;
    const float* W = W1; int K = K1;
    unsigned short* WH = WtH1; unsigned short* WL = WtL1;
    int li = idx;
    if (idx >= 128 * KP) { W = W2; K = K2; WH = WtH2; WL = WtL2; li = idx - 128 * KP; }
    int n = li >> 7;          // KP==128
    int k = li & (KP - 1);
    float v = (k < K) ? W[(size_t)k * 128 + n] : 0.0f;
    unsigned short hi = f2bf(v);
    float fhi = bf2f(hi);
    unsigned short lo = f2bf(v - fhi);
    WH[li] = hi;
    WL[li] = lo;
}

// ---------------- MFMA GEMM: hb = bf16( (A@W) * dinv[row] ), split-bf16 3-term ----
// 4 waves: wave w owns rows (w&1)*16..+15 of a 32-row block, col half (w>>1)*64..+63.
__global__ __launch_bounds__(256) void gemm_mfma(
    const float* __restrict__ A, int K, int M,
    const unsigned short* __restrict__ WtH, const unsigned short* __restrict__ WtL,
    const float* __restrict__ dinv, unsigned int* __restrict__ hb)
{
    const int w    = threadIdx.x >> 6;
    const int lane = threadIdx.x & 63;
    const int row_in = lane & 15;     // A row within 16 / B col within 16
    const int kgrp   = lane >> 4;     // 0..3 (8 k's each)
    const int wrow = w & 1;
    const int wcol = w >> 1;
    const int m = blockIdx.x * 32 + wrow * 16 + row_in;

    f32x4 acc[4];
#pragma unroll
    for (int j = 0; j < 4; j++) acc[j] = (f32x4){0.f, 0.f, 0.f, 0.f};

    for (int k0 = 0; k0 < K; k0 += 32) {
        int kb = k0 + kgrp * 8;
        float av[8];
#pragma unroll
        for (int i = 0; i < 8; i++) av[i] = 0.f;
        if (m < M) {
            if (kb + 8 <= K) {
                const float4* p = reinterpret_cast<const float4*>(A + (size_t)m * K + kb);
                float4 x0 = p[0], x1 = p[1];
                av[0] = x0.x; av[1] = x0.y; av[2] = x0.z; av[3] = x0.w;
                av[4] = x1.x; av[5] = x1.y; av[6] = x1.z; av[7] = x1.w;
            } else {
#pragma unroll
                for (int i = 0; i < 8; i++)
                    if (kb + i < K) av[i] = A[(size_t)m * K + kb + i];
            }
        }
        union { unsigned short u[8]; bf16x8 v; } ah, al;
#pragma unroll
        for (int i = 0; i < 8; i++) {
            unsigned short h = f2bf(av[i]);
            ah.u[i] = h;
            al.u[i] = f2bf(av[i] - bf2f(h));
        }
        // prefetch all B fragments for this k-slice (independent loads)
        bf16x8 bh[4], bl[4];
#pragma unroll
        for (int j = 0; j < 4; j++) {
            const int nb = wcol * 4 + j;
            const size_t wo = (size_t)(nb * 16 + row_in) * KP + kb;
            bh[j] = *reinterpret_cast<const bf16x8*>(WtH + wo);
            bl[j] = *reinterpret_cast<const bf16x8*>(WtL + wo);
        }
#pragma unroll
        for (int j = 0; j < 4; j++) {
            acc[j] = __builtin_amdgcn_mfma_f32_16x16x32_bf16(ah.v, bh[j], acc[j], 0, 0, 0);
            acc[j] = __builtin_amdgcn_mfma_f32_16x16x32_bf16(ah.v, bl[j], acc[j], 0, 0, 0);
            acc[j] = __builtin_amdgcn_mfma_f32_16x16x32_bf16(al.v, bh[j], acc[j], 0, 0, 0);
        }
    }

    // epilogue: C/D layout col=lane&15, row=kgrp*4+r  -> LDS -> packed bf16 store
    __shared__ float C[32][132];
#pragma unroll
    for (int j = 0; j < 4; j++) {
        const int nb = wcol * 4 + j;
#pragma unroll
        for (int r = 0; r < 4; r++)
            C[wrow * 16 + kgrp * 4 + r][nb * 16 + row_in] = acc[j][r];
    }
    __syncthreads();

    int row = threadIdx.x >> 3;          // 0..31
    int c0  = (threadIdx.x & 7) * 16;    // 0..112
    int gm  = blockIdx.x * 32 + row;
    if (gm < M) {
        float dv = dinv[gm];
        unsigned int* orow = hb + (size_t)gm * 64 + (c0 >> 1);
#pragma unroll
        for (int q = 0; q < 2; q++) {
            float4 v0 = *reinterpret_cast<float4*>(&C[row][c0 + q * 8]);
            float4 v1 = *reinterpret_cast<float4*>(&C[row][c0 + q * 8 + 4]);
            uint4 pk;
            pk.x = (unsigned int)f2bf(v0.x * dv) | ((unsigned int)f2bf(v0.y * dv) << 16);
            pk.y = (unsigned int)f2bf(v0.z * dv) | ((unsigned int)f2bf(v0.w * dv) << 16);
            pk.z = (unsigned int)f2bf(v1.x * dv) | ((unsigned int)f2bf(v1.y * dv) << 16);
            pk.w = (unsigned int)f2bf(v1.z * dv) | ((unsigned int)f2bf(v1.w * dv) << 16);
            *reinterpret_cast<uint4*>(orow + q * 4) = pk;
        }
    }
}

// ---- gather: out[d] = relu( dd * (sum_{e:dst=d} h'[src] + h'[d]) + b ), h' in bf16 ----
__global__ __launch_bounds__(256) void gather_agg(
    const uint2* __restrict__ hp, const float* __restrict__ dinv,
    const int* __restrict__ off, const int* __restrict__ deg,
    const int* __restrict__ csr_src,
    const float* __restrict__ bias, float* __restrict__ out)
{
    int gid = blockIdx.x * 256 + threadIdx.x;
    int node = gid >> 5;
    if (node >= N_NODES) return;
    int lane = gid & 31;

    int beg = off[node];
    int end = beg + deg[node];
    float dd = dinv[node];

    uint2 self = hp[(size_t)node * 32 + lane];
    float4 a0 = make_float4(bflo(self.x), bfhi(self.x), bflo(self.y), bfhi(self.y));
    float4 a1 = make_float4(0.f, 0.f, 0.f, 0.f);
    float4 a2 = make_float4(0.f, 0.f, 0.f, 0.f);
    float4 a3 = make_float4(0.f, 0.f, 0.f, 0.f);

    int j = beg;
    for (; j + 3 < end; j += 4) {
        int s0 = csr_src[j + 0];
        int s1 = csr_src[j + 1];
        int s2 = csr_src[j + 2];
        int s3 = csr_src[j + 3];
        uint2 v0 = hp[(size_t)s0 * 32 + lane];
        uint2 v1 = hp[(size_t)s1 * 32 + lane];
        uint2 v2 = hp[(size_t)s2 * 32 + lane];
        uint2 v3 = hp[(size_t)s3 * 32 + lane];
        a0.x += bflo(v0.x); a0.y += bfhi(v0.x); a0.z += bflo(v0.y); a0.w += bfhi(v0.y);
        a1.x += bflo(v1.x); a1.y += bfhi(v1.x); a1.z += bflo(v1.y); a1.w += bfhi(v1.y);
        a2.x += bflo(v2.x); a2.y += bfhi(v2.x); a2.z += bflo(v2.y); a2.w += bfhi(v2.y);
        a3.x += bflo(v3.x); a3.y += bfhi(v3.x); a3.z += bflo(v3.y); a3.w += bfhi(v3.y);
    }
    for (; j < end; ++j) {
        int s = csr_src[j];
        uint2 v = hp[(size_t)s * 32 + lane];
        a0.x += bflo(v.x); a0.y += bfhi(v.x); a0.z += bflo(v.y); a0.w += bfhi(v.y);
    }
    a0.x += a1.x + a2.x + a3.x;
    a0.y += a1.y + a2.y + a3.y;
    a0.z += a1.z + a2.z + a3.z;
    a0.w += a1.w + a2.w + a3.w;

    float4 bb = *reinterpret_cast<const float4*>(bias + lane * 4);
    float4 o = make_float4(fmaxf(a0.x * dd + bb.x, 0.f),
                           fmaxf(a0.y * dd + bb.y, 0.f),
                           fmaxf(a0.z * dd + bb.z, 0.f),
                           fmaxf(a0.w * dd + bb.w, 0.f));
    *reinterpret_cast<float4*>(out + (size_t)node * HID + lane * 4) = o;
}

// ---------------- fused mean-pool + head ----------------
__global__ __launch_bounds__(128) void pool_head(
    const float* __restrict__ xbuf, const int* __restrict__ starts,
    const float* __restrict__ Wp, const float* __restrict__ bp,
    float* __restrict__ out)
{
    __shared__ float p[128];
    int g = blockIdx.x;
    int t = threadIdx.x;
    int s0 = starts[g], s1 = starts[g + 1];
    float acc = 0.f;
    for (int n = s0; n < s1; ++n) acc += xbuf[(size_t)n * HID + t];
    float cntf = (float)(s1 - s0);
    p[t] = acc / fmaxf(cntf, 1.0f);
    __syncthreads();
    float o = bp[t];
#pragma unroll 8
    for (int k = 0; k < HID; k++) o += p[k] * Wp[(size_t)k * OUT_DIM + t];
    out[(size_t)g * OUT_DIM + t] = o;
}

extern "C" void kernel_launch(void* const* d_in, const int* in_sizes, int n_in,
                              void* d_out, int out_size, void* d_ws, size_t ws_size,
                              hipStream_t stream) {
    const float* x   = (const float*)d_in[0];
    const int*   ei  = (const int*)d_in[1];
    const int*   src = ei;
    const int*   dst = ei + N_EDGES;
    const int*   batch = (const int*)d_in[2];
    const float* W1 = (const float*)d_in[3];
    const float* b1 = (const float*)d_in[4];
    const float* W2 = (const float*)d_in[5];
    const float* b2 = (const float*)d_in[6];
    const float* Wp = (const float*)d_in[7];
    const float* bp = (const float*)d_in[8];
    float* out = (float*)d_out;

    // ---- workspace layout (4-byte units) ----
    float* ws     = (float*)d_ws;
    float* dinv   = ws;                          // 50,048
    int*   deg    = (int*)(ws + 50048);          // 50,048
    int*   total  = deg + 50048;                 // 32 (1 used)
    int*   off    = total + 32;                  // 50,056
    int*   csr_src= off + 50056;                 // 600,000
    int*   starts = csr_src + 600000;            // 1,024 (1001 used)
    unsigned short* wt1h = (unsigned short*)(starts + 1024);   // 16,384 u16 each
    unsigned short* wt1l = wt1h + 128 * KP;
    unsigned short* wt2h = wt1l + 128 * KP;
    unsigned short* wt2l = wt2h + 128 * KP;
    unsigned int* hb = (unsigned int*)(wt2l + 128 * KP);       // 3,200,000 u32
    float* xbuf   = (float*)(hb + 3200000);      // 6,400,000 f
    // alias: cursor lives in xbuf until gather1 writes xbuf
    int*   cursor = (int*)xbuf;

    // ---- CSR build (no hipMemset: zero_meta + cursor zeroed in alloc_off) ----
    zero_meta<<<(50080 / 4 + 255) / 256, 256, 0, stream>>>(deg);
    deg_count<<<(N_EDGES + 255) / 256, 256, 0, stream>>>(dst, deg);
    alloc_off<<<(N_NODES + 255) / 256, 256, 0, stream>>>(deg, off, total, dinv, cursor);
    fill_csr<<<(N_EDGES + 255) / 256, 256, 0, stream>>>(src, dst, off, cursor, csr_src);
    graph_bounds<<<(N_NODES + 255) / 256, 256, 0, stream>>>(batch, starts);

    // ---- weight prep (both layers, one launch) ----
    conv_w2<<<(2 * 128 * KP + 255) / 256, 256, 0, stream>>>(W1, IN_DIM, W2, HID,
                                                            wt1h, wt1l, wt2h, wt2l);

    const int gemm_blocks = (N_NODES + 31) / 32;
    const int gather_blocks = (N_NODES * 32 + 255) / 256;

    // ---- layer 1 ----
    gemm_mfma<<<gemm_blocks, 256, 0, stream>>>(x, IN_DIM, N_NODES, wt1h, wt1l, dinv, hb);
    gather_agg<<<gather_blocks, 256, 0, stream>>>((const uint2*)hb, dinv, off, deg, csr_src, b1, xbuf);

    // ---- layer 2 ----
    gemm_mfma<<<gemm_blocks, 256, 0, stream>>>(xbuf, HID, N_NODES, wt2h, wt2l, dinv, hb);
    gather_agg<<<gather_blocks, 256, 0, stream>>>((const uint2*)hb, dinv, off, deg, csr_src, b2, xbuf);

    // ---- pool + head ----
    pool_head<<<N_GRAPHS, 128, 0, stream>>>(xbuf, starts, Wp, bp, out);
}